// Round 17
// baseline (412.625 us; speedup 1.0000x reference)
//
#include <hip/hip_runtime.h>
#include <hip/hip_bf16.h>
#include <math.h>

// TransformerBlock fp32 in/out; internal bf16 MFMA compute.
// B=8, N=1024, D=768, H=12, hd=64, HIDDEN=3072, EPS=1e-6
//
// R15 (resubmit; prior round hit GPUAcquisitionTimeout, never measured).
// gemm_w128 -> 3-slot LDS ring, depth-2 prefetch, counted vmcnt(16)
// (never drains to 0 mid-loop), raw s_barrier. Isolates T3/T4 from R3's
// confounds (depth-3, 4 slots, LDS blowup). At step kt: stage tile kt+2 into
// slot (kt+2)%3 (readers done at step kt-1's closing barrier), wait vmcnt(16)
// = only tile kt (issued 2 steps ago) must land; tiles kt+1,kt+2 stay in
// flight across the barrier. n64/attn/pre/ln unchanged from R14-best (347.8).

#define DIM 768
#define SEQ 1024
#define BATCH 8
#define NHEAD 12
#define HDIM 64
#define HID 3072
#define MTOK (BATCH * SEQ)  // 8192

typedef __attribute__((ext_vector_type(8))) short short8;
typedef __attribute__((ext_vector_type(4))) short short4v;
typedef __attribute__((ext_vector_type(4))) float floatx4;

__device__ __forceinline__ short f2s(float x) {
  __hip_bfloat16 h = __float2bfloat16(x);
  return __builtin_bit_cast(short, h);
}
__device__ __forceinline__ float s2f(short s) {
  return __bfloat162float(__builtin_bit_cast(__hip_bfloat16, s));
}
__device__ __forceinline__ floatx4 zf4() {
  floatx4 v; v[0] = v[1] = v[2] = v[3] = 0.f; return v;
}
__device__ __forceinline__ float gelu_f(float x) {
  float z = 0.7978845608028654f * (x + 0.044715f * x * x * x);
  float u = __expf(2.f * z);
  return 0.5f * x * (2.f - 2.f / (u + 1.f));
}

// ---------- wave-per-row LayerNorm body (row fits one wave: 768 = 12x64) ----------
__device__ __forceinline__ void ln_row(const float* __restrict__ xr,
                                       const float* __restrict__ ls,
                                       const float* __restrict__ lb,
                                       short* __restrict__ yr, int lane) {
  float v[12];
  float s1 = 0.f, s2 = 0.f;
#pragma unroll
  for (int j = 0; j < 12; ++j) {
    v[j] = xr[lane + j * 64];
    s1 += v[j];
    s2 += v[j] * v[j];
  }
#pragma unroll
  for (int off = 32; off; off >>= 1) {
    s1 += __shfl_xor(s1, off, 64);
    s2 += __shfl_xor(s2, off, 64);
  }
  const float mu = s1 * (1.0f / DIM);
  const float var = s2 * (1.0f / DIM) - mu * mu;
  const float rstd = rsqrtf(fmaxf(var, 0.f) + 1e-6f);
#pragma unroll
  for (int j = 0; j < 12; ++j) {
    const int idx = lane + j * 64;
    yr[idx] = f2s((v[j] - mu) * rstd * ls[idx] + lb[idx]);
  }
}

// ---------- merged prologue: weight transposes (4 tiles/block) + LN1 (4 rows/block) ----------
__global__ __launch_bounds__(256) void pre_kernel(
    const float* __restrict__ w0, short* __restrict__ o0,
    const float* __restrict__ w1, short* __restrict__ o1,
    const float* __restrict__ w2, short* __restrict__ o2,
    const float* __restrict__ w3, short* __restrict__ o3,
    const float* __restrict__ x, const float* __restrict__ ls,
    const float* __restrict__ lb, short* __restrict__ y) {
  const int id = blockIdx.x;
  const int t = threadIdx.x;
  if (id < 1728) {
    __shared__ float tile[32][33];
    const int tx = t & 31, ty = t >> 5;
#pragma unroll
    for (int it = 0; it < 4; ++it) {
      const int gid = id * 4 + it;
      const float* in;
      short* out;
      int K, N, tid;
      if (gid < 1728)      { in = w0; out = o0; K = DIM; N = 3 * DIM; tid = gid; }
      else if (gid < 2304) { in = w1; out = o1; K = DIM; N = DIM;     tid = gid - 1728; }
      else if (gid < 4608) { in = w2; out = o2; K = DIM; N = HID;     tid = gid - 2304; }
      else                 { in = w3; out = o3; K = HID; N = DIM;     tid = gid - 4608; }
      const int ntx = N >> 5;
      const int n0 = (tid % ntx) * 32, k0 = (tid / ntx) * 32;
      if (it) __syncthreads();
#pragma unroll
      for (int i = 0; i < 4; ++i)
        tile[ty + i * 8][tx] = in[(size_t)(k0 + ty + i * 8) * N + n0 + tx];
      __syncthreads();
#pragma unroll
      for (int i = 0; i < 4; ++i)
        out[(size_t)(n0 + ty + i * 8) * K + k0 + tx] = f2s(tile[tx][ty + i * 8]);
    }
  } else {
    const int row = (id - 1728) * 4 + (t >> 6);
    const int lane = t & 63;
    ln_row(x + (size_t)row * DIM, ls, lb, y + (size_t)row * DIM, lane);
  }
}

// ---------- LayerNorm (standalone, for LN2): wave-per-row, 4 rows/block ----------
__global__ __launch_bounds__(256) void ln_kernel(const float* __restrict__ x,
                                                 const float* __restrict__ scale,
                                                 const float* __restrict__ bias,
                                                 short* __restrict__ y) {
  const int row = blockIdx.x * 4 + (threadIdx.x >> 6);
  const int lane = threadIdx.x & 63;
  ln_row(x + (size_t)row * DIM, scale, bias, y + (size_t)row * DIM, lane);
}

// ---------- async staging, 64-wide rows (8 chunks), xor-swizzled ----------
template <int ROWS, int THREADS>
__device__ __forceinline__ void stage8(const short* __restrict__ src, int ld,
                                       short* lds, int t) {
#pragma unroll
  for (int i = 0; i < (ROWS * 8) / THREADS; ++i) {
    const int S = i * THREADS + t;
    const int row = S >> 3;
    const int chunk = (S & 7) ^ (row & 7);
    const short* g = src + (size_t)row * ld + chunk * 8;
    const unsigned off = __builtin_amdgcn_readfirstlane((unsigned)((S & ~63) * 16));
    __builtin_amdgcn_global_load_lds(
        (const __attribute__((address_space(1))) void*)g,
        (__attribute__((address_space(3))) void*)((char*)lds + off), 16, 0, 0);
  }
}

// ---------- wide MFMA GEMM: 128x128 tile, 256 threads, BK=64, 3-slot ring ----------
// Counted vmcnt: per wave, 8 load-insts/tile; after staging kt+2 there are 24
// outstanding; vmcnt(16) completes exactly tile kt (oldest), leaving kt+1 and
// kt+2 in flight across the raw barrier. K must be 768 (nk=12, %3==0).
// MODE 0: qkv split -> Qb/Kb [bh][1024][64], Vtb [bh][64][1024]
// MODE 2: bf16 out + gelu
template <int MODE>
__global__ __launch_bounds__(256) void gemm_w128(
    const short* __restrict__ A, const short* __restrict__ Bt,
    const float* __restrict__ bias,
    short* __restrict__ outB,
    short* __restrict__ Qb, short* __restrict__ Kb, short* __restrict__ Vtb,
    int N, int K) {
  __shared__ __align__(16) short Asm[3][8192];   // 3 x 128x64 = 48 KB
  __shared__ __align__(16) short Bsm[3][8192];   // 3 x 128x64 = 48 KB
  const int t = threadIdx.x;
  const int lane = t & 63, w = t >> 6, quad = lane >> 4, l15 = lane & 15;

  const int nbx = gridDim.x;
  const int lid = blockIdx.y * nbx + blockIdx.x;
  const int xcd = lid & 7, local = lid >> 3;
  const int m0 = ((local / nbx) * 8 + xcd) * 128;
  const int n0 = (local % nbx) * 128;
  const int mb = (w & 1) * 64, nb = (w >> 1) * 64;

  floatx4 acc[4][4];
#pragma unroll
  for (int mi = 0; mi < 4; ++mi)
#pragma unroll
    for (int ni = 0; ni < 4; ++ni) acc[mi][ni] = zf4();

  const short* Ab = A + (size_t)m0 * K;
  const short* Bb = Bt + (size_t)n0 * K;
  const int nk = K >> 6;  // 12 (K=768 at both call sites; 12 % 3 == 0)

  // prologue: tiles 0,1 into slots 0,1 (8 load-insts/wave each)
  stage8<128, 256>(Ab, K, Asm[0], t);       stage8<128, 256>(Bb, K, Bsm[0], t);
  stage8<128, 256>(Ab + 64, K, Asm[1], t);  stage8<128, 256>(Bb + 64, K, Bsm[1], t);

#define W128_STEP(SLOT) do { \
  _Pragma("unroll") for (int ks = 0; ks < 2; ++ks) { \
    short8 a_[4], b_[4]; \
    _Pragma("unroll") for (int mi = 0; mi < 4; ++mi) { \
      const int r = mb + mi * 16 + l15; \
      a_[mi] = *(const short8*)(Asm[SLOT] + r * 64 + (((ks * 4 + quad) ^ (r & 7)) * 8)); \
    } \
    _Pragma("unroll") for (int ni = 0; ni < 4; ++ni) { \
      const int r = nb + ni * 16 + l15; \
      b_[ni] = *(const short8*)(Bsm[SLOT] + r * 64 + (((ks * 4 + quad) ^ (r & 7)) * 8)); \
    } \
    _Pragma("unroll") for (int mi = 0; mi < 4; ++mi) \
      _Pragma("unroll") for (int ni = 0; ni < 4; ++ni) \
        acc[mi][ni] = __builtin_amdgcn_mfma_f32_16x16x32_bf16(a_[mi], b_[ni], acc[mi][ni], 0, 0, 0); \
  } \
} while (0)

// step J: stage tile J+2 into slot NXT=(J+2)%3 (its readers finished at step
// J-1's closing barrier), counted wait, barrier, compute slot CUR=J%3, barrier.
#define W128_IT(J, CUR, NXT) do { \
  if ((J) + 2 < nk) { \
    stage8<128, 256>(Ab + ((J) + 2) * 64, K, Asm[NXT], t); \
    stage8<128, 256>(Bb + ((J) + 2) * 64, K, Bsm[NXT], t); \
    asm volatile("s_waitcnt vmcnt(16)" ::: "memory"); \
  } else if ((J) + 1 < nk) { \
    asm volatile("s_waitcnt vmcnt(8)" ::: "memory"); \
  } else { \
    asm volatile("s_waitcnt vmcnt(0)" ::: "memory"); \
  } \
  __builtin_amdgcn_s_barrier(); \
  W128_STEP(CUR); \
  __builtin_amdgcn_s_barrier(); \
} while (0)

  for (int kt = 0; kt < nk; kt += 3) {
    W128_IT(kt + 0, 0, 2);
    W128_IT(kt + 1, 1, 0);
    W128_IT(kt + 2, 2, 1);
  }

#pragma unroll
  for (int mi = 0; mi < 4; ++mi) {
    const int row0 = m0 + mb + mi * 16 + quad * 4;
#pragma unroll
    for (int ni = 0; ni < 4; ++ni) {
      const int col = n0 + nb + ni * 16 + l15;
      const float bv = bias[col];
      float v[4];
#pragma unroll
      for (int r = 0; r < 4; ++r) v[r] = acc[mi][ni][r] + bv;
      if (MODE == 0) {
        const int bb = row0 >> 10;
        const int s0 = row0 & 1023;
        if (col < 1536) {
          const int cc = (col < 768) ? col : col - 768;
          const int h = cc >> 6, d = cc & 63;
          short* dst = (col < 768 ? Qb : Kb) + (size_t)(bb * NHEAD + h) * SEQ * HDIM;
#pragma unroll
          for (int r = 0; r < 4; ++r) dst[(size_t)(s0 + r) * HDIM + d] = f2s(v[r]);
        } else {
          const int cc = col - 1536;
          const int h = cc >> 6, d = cc & 63;
          short4v pv;
#pragma unroll
          for (int r = 0; r < 4; ++r) pv[r] = f2s(v[r]);
          *(short4v*)(Vtb + ((size_t)(bb * NHEAD + h) * HDIM + d) * SEQ + s0) = pv;
        }
      } else {
#pragma unroll
        for (int r = 0; r < 4; ++r)
          outB[(size_t)(row0 + r) * N + col] = f2s(gelu_f(v[r]));
      }
    }
  }
}

// ---------- MFMA GEMM (narrow N=64 tiles): 128x64 tile, 2 waves, BK=64 ----------
// (byte-identical to the R0 baseline; unchanged control)
__global__ __launch_bounds__(128) void gemm_n64(
    const short* __restrict__ A, const short* __restrict__ Bt,
    const float* __restrict__ bias, const float* __restrict__ res,
    float* __restrict__ outF, int N, int K) {
  __shared__ __align__(16) short Asm[2][8192];   // 128 x 64
  __shared__ __align__(16) short Bsm[2][4096];   // 64 x 64
  const int t = threadIdx.x;
  const int lane = t & 63, w = t >> 6, quad = lane >> 4, l15 = lane & 15;

  const int nbx = gridDim.x;   // 12
  const int lid = blockIdx.y * nbx + blockIdx.x;
  const int xcd = lid & 7, local = lid >> 3;
  const int m0 = ((local / nbx) * 8 + xcd) * 128;
  const int n0 = (local % nbx) * 64;
  const int mb = w * 64;

  floatx4 acc[4][4];
#pragma unroll
  for (int mi = 0; mi < 4; ++mi)
#pragma unroll
    for (int ni = 0; ni < 4; ++ni) acc[mi][ni] = zf4();

  stage8<128, 128>(A + (size_t)m0 * K, K, Asm[0], t);
  stage8<64, 128>(Bt + (size_t)n0 * K, K, Bsm[0], t);

  const int nk = K >> 6;
  for (int kt = 0; kt < nk; ++kt) {
    __syncthreads();
    const int cur = kt & 1;
    if (kt + 1 < nk) {
      stage8<128, 128>(A + (size_t)m0 * K + (kt + 1) * 64, K, Asm[cur ^ 1], t);
      stage8<64, 128>(Bt + (size_t)n0 * K + (kt + 1) * 64, K, Bsm[cur ^ 1], t);
    }
#pragma unroll
    for (int ks = 0; ks < 2; ++ks) {
      short8 a[4], b[4];
#pragma unroll
      for (int mi = 0; mi < 4; ++mi) {
        const int r = mb + mi * 16 + l15;
        a[mi] = *(const short8*)(Asm[cur] + r * 64 + (((ks * 4 + quad) ^ (r & 7)) * 8));
      }
#pragma unroll
      for (int ni = 0; ni < 4; ++ni) {
        const int r = ni * 16 + l15;
        b[ni] = *(const short8*)(Bsm[cur] + r * 64 + (((ks * 4 + quad) ^ (r & 7)) * 8));
      }
#pragma unroll
      for (int mi = 0; mi < 4; ++mi)
#pragma unroll
        for (int ni = 0; ni < 4; ++ni)
          acc[mi][ni] = __builtin_amdgcn_mfma_f32_16x16x32_bf16(a[mi], b[ni], acc[mi][ni], 0, 0, 0);
    }
  }

#pragma unroll
  for (int mi = 0; mi < 4; ++mi) {
    const int row0 = m0 + mb + mi * 16 + quad * 4;
#pragma unroll
    for (int ni = 0; ni < 4; ++ni) {
      const int col = n0 + ni * 16 + l15;
      const float bv = bias[col];
#pragma unroll
      for (int r = 0; r < 4; ++r) {
        const size_t idx = (size_t)(row0 + r) * N + col;
        outF[idx] = acc[mi][ni][r] + bv + res[idx];
      }
    }
  }
}

// ---------- attention: S^T = K Q^T, O^T = V^T P^T; KT=64, double-buffered ----------
// (byte-identical to the R0 baseline)
__device__ __forceinline__ void stage64(const short* __restrict__ src, int ld,
                                        short* lds, int t) {
  const int lane = t & 63, w = t >> 6;
#pragma unroll
  for (int i = 0; i < 2; ++i) {
    const int S = w * 128 + i * 64 + lane;
    const int r = S >> 3, c0 = S & 7;
    const int c = c0 ^ (r & 7);
    const short* g = src + (size_t)r * ld + c * 8;
    const unsigned off = __builtin_amdgcn_readfirstlane((unsigned)((w * 128 + i * 64) * 16));
    __builtin_amdgcn_global_load_lds(
        (const __attribute__((address_space(1))) void*)g,
        (__attribute__((address_space(3))) void*)((char*)lds + off), 16, 0, 0);
  }
}

__global__ __launch_bounds__(256) void attn_kernel(
    const short* __restrict__ Qb, const short* __restrict__ Kb,
    const short* __restrict__ Vtb, short* __restrict__ o) {
  __shared__ __align__(16) short Ks[2][4096];
  __shared__ __align__(16) short Vts[2][4096];
  __shared__ __align__(16) short Pt[8192];
  const int t = threadIdx.x;
  const int lane = t & 63, w = t >> 6, quad = lane >> 4, l15 = lane & 15;
  const int bh = blockIdx.x;           // 0..95
  const int q0 = blockIdx.y * 128;     // 0..7 tiles
  const size_t qkbase = (size_t)bh * SEQ * HDIM;
  const size_t vbase = (size_t)bh * HDIM * SEQ;
  short* ptw = Pt + w * 2048;
  const float cexp = 0.18033688011f;  // 0.125 * log2(e)

  short8 bq[2][2];
#pragma unroll
  for (int mi = 0; mi < 2; ++mi)
#pragma unroll
    for (int ks = 0; ks < 2; ++ks)
      bq[mi][ks] = *(const short8*)(Qb + qkbase +
                                    (size_t)(q0 + w * 32 + mi * 16 + l15) * HDIM +
                                    ks * 32 + quad * 8);

  floatx4 oacc[4][2];
  float l_acc[2] = {0.f, 0.f};
#pragma unroll
  for (int di = 0; di < 4; ++di)
#pragma unroll
    for (int mi = 0; mi < 2; ++mi) oacc[di][mi] = zf4();

  stage64(Kb + qkbase, HDIM, Ks[0], t);
  stage64(Vtb + vbase, SEQ, Vts[0], t);

  for (int kt = 0; kt < 16; ++kt) {
    __syncthreads();
    const int cur = kt & 1;
    if (kt < 15) {
      stage64(Kb + qkbase + (size_t)(kt + 1) * 64 * HDIM, HDIM, Ks[cur ^ 1], t);
      stage64(Vtb + vbase + (kt + 1) * 64, SEQ, Vts[cur ^ 1], t);
    }

    floatx4 sacc[4][2];
#pragma unroll
    for (int ni = 0; ni < 4; ++ni)
#pragma unroll
      for (int mi = 0; mi < 2; ++mi) sacc[ni][mi] = zf4();
#pragma unroll
    for (int ks = 0; ks < 2; ++ks) {
      short8 ak[4];
#pragma unroll
      for (int ni = 0; ni < 4; ++ni) {
        const int r = ni * 16 + l15;
        ak[ni] = *(const short8*)(Ks[cur] + r * 64 + (((ks * 4 + quad) ^ (r & 7)) * 8));
      }
#pragma unroll
      for (int ni = 0; ni < 4; ++ni)
#pragma unroll
        for (int mi = 0; mi < 2; ++mi)
          sacc[ni][mi] = __builtin_amdgcn_mfma_f32_16x16x32_bf16(ak[ni], bq[mi][ks], sacc[ni][mi], 0, 0, 0);
    }

#pragma unroll
    for (int mi = 0; mi < 2; ++mi) {
      const int row = mi * 16 + l15;
      const int swz = (row & 7) ^ ((row & 8) >> 1);
#pragma unroll
      for (int ni = 0; ni < 4; ++ni) {
        short4v pk;
#pragma unroll
        for (int r = 0; r < 4; ++r) {
          const float p = exp2f(sacc[ni][mi][r] * cexp);
          l_acc[mi] += p;
          pk[r] = f2s(p);
        }
        const int c = ni * 2 + (quad >> 1);
        *(short4v*)(ptw + row * 64 + ((c ^ swz) * 8 + (quad & 1) * 4)) = pk;
      }
    }

#pragma unroll
    for (int ks = 0; ks < 2; ++ks) {
      short8 bp[2];
#pragma unroll
      for (int mi = 0; mi < 2; ++mi) {
        const int row = mi * 16 + l15;
        const int swz = (row & 7) ^ ((row & 8) >> 1);
        bp[mi] = *(const short8*)(ptw + row * 64 + (((ks * 4 + quad) ^ swz) * 8));
      }
      short8 av[4];
#pragma unroll
      for (int di = 0; di < 4; ++di) {
        const int r = di * 16 + l15;
        av[di] = *(const short8*)(Vts[cur] + r * 64 + (((ks * 4 + quad) ^ (r & 7)) * 8));
      }
#pragma unroll
      for (int di = 0; di < 4; ++di)
#pragma unroll
        for (int mi = 0; mi < 2; ++mi)
          oacc[di][mi] = __builtin_amdgcn_mfma_f32_16x16x32_bf16(av[di], bp[mi], oacc[di][mi], 0, 0, 0);
    }
  }

  const int bb = bh / NHEAD, hh = bh % NHEAD;
  float inv[2];
#pragma unroll
  for (int mi = 0; mi < 2; ++mi) {
    float l = l_acc[mi];
    l += __shfl_xor(l, 16, 64);
    l += __shfl_xor(l, 32, 64);
    inv[mi] = 1.0f / l;
  }
#pragma unroll
  for (int di = 0; di < 4; ++di)
#pragma unroll
    for (int mi = 0; mi < 2; ++mi) {
      const int tok = bb * SEQ + q0 + w * 32 + mi * 16 + l15;
      const int d = hh * HDIM + di * 16 + quad * 4;
      short4v ov;
#pragma unroll
      for (int r = 0; r < 4; ++r) ov[r] = f2s(oacc[di][mi][r] * inv[mi]);
      *(short4v*)(o + (size_t)tok * DIM + d) = ov;
    }
}

extern "C" void kernel_launch(void* const* d_in, const int* in_sizes, int n_in,
                              void* d_out, int out_size, void* d_ws, size_t ws_size,
                              hipStream_t stream) {
  const float* x      = (const float*)d_in[0];
  const float* ln1_s  = (const float*)d_in[1];
  const float* ln1_b  = (const float*)d_in[2];
  const float* qkv_w  = (const float*)d_in[3];
  const float* qkv_b  = (const float*)d_in[4];
  const float* proj_w = (const float*)d_in[5];
  const float* proj_b = (const float*)d_in[6];
  const float* ln2_s  = (const float*)d_in[7];
  const float* ln2_b  = (const float*)d_in[8];
  const float* fc1_w  = (const float*)d_in[9];
  const float* fc1_b  = (const float*)d_in[10];
  const float* fc2_w  = (const float*)d_in[11];
  const float* fc2_b  = (const float*)d_in[12];
  float* out = (float*)d_out;

  char* p = (char*)d_ws;
  short* wqt = (short*)p; p += (size_t)(3 * DIM) * DIM * 2;
  short* wpt = (short*)p; p += (size_t)DIM * DIM * 2;
  short* w1t = (short*)p; p += (size_t)HID * DIM * 2;
  short* w2t = (short*)p; p += (size_t)DIM * HID * 2;
  short* y   = (short*)p; p += (size_t)MTOK * DIM * 2;
  short* Qb  = (short*)p; p += (size_t)MTOK * DIM * 2;
  short* Kb  = (short*)p; p += (size_t)MTOK * DIM * 2;
  short* Vtb = (short*)p; p += (size_t)MTOK * DIM * 2;
  float* x1  = (float*)p; p += (size_t)MTOK * DIM * 4;
  short* h   = (short*)p; p += (size_t)MTOK * HID * 2;
  short* obuf = y;
  short* y2   = Qb;

  // prologue: weight transposes (4 tiles/block) + LN1 (wave-per-row) merged
  pre_kernel<<<1728 + MTOK / 4, 256, 0, stream>>>(qkv_w, wqt, proj_w, wpt, fc1_w, w1t,
                                                  fc2_w, w2t, x, ln1_s, ln1_b, y);
  // qkv: 128x128 tiles (2304 = 18 x 128), K=768 (nk=12)
  gemm_w128<0><<<dim3(18, 64), 256, 0, stream>>>(
      y, wqt, qkv_b, nullptr, Qb, Kb, Vtb, 3 * DIM, DIM);
  // attention: grid (bh, qt) for XCD L2 reuse of K/V
  attn_kernel<<<dim3(BATCH * NHEAD, SEQ / 128), 256, 0, stream>>>(Qb, Kb, Vtb, obuf);
  gemm_n64<<<dim3(12, 64), 128, 0, stream>>>(
      obuf, wpt, proj_b, x, x1, DIM, DIM);
  ln_kernel<<<MTOK / 4, 256, 0, stream>>>(x1, ln2_s, ln2_b, y2);
  // fc1: 128x128 tiles (3072 = 24 x 128), K=768 (nk=12)
  gemm_w128<2><<<dim3(24, 64), 256, 0, stream>>>(
      y2, w1t, fc1_b, h, nullptr, nullptr, nullptr, HID, DIM);
  gemm_n64<<<dim3(12, 64), 128, 0, stream>>>(
      h, w2t, fc2_b, x1, out, DIM, HID);
}

// Round 18
// 345.698 us; speedup vs baseline: 1.1936x; 1.1936x over previous
//
#include <hip/hip_runtime.h>
#include <hip/hip_bf16.h>
#include <math.h>

// TransformerBlock fp32 in/out; internal bf16 MFMA compute.
// B=8, N=1024, D=768, H=12, hd=64, HIDDEN=3072, EPS=1e-6
//
// R17: REVERT to R14-best (347.8us). R15's counted-vmcnt ring hit both
// pre-committed falsifiers (fc1 105.9us, FETCH 120MB) — 3rd confirmation
// that prefetch-depth>1 blows L2 locality at this shape. Ledger: 10 measured
// GEMM variants, MfmaUtil pinned 21-23% for all viable configs; structure is
// bracketed. This submission consolidates the verified best state:
// - wide GEMM: 128x128 tile, BK=64, 2-buffer, vmcnt(0)+syncthreads
// - narrow GEMM: 128x64, BK=64 (R0 structure)
// - attn: R0 structure; pre/ln: wave-per-row (R9)

#define DIM 768
#define SEQ 1024
#define BATCH 8
#define NHEAD 12
#define HDIM 64
#define HID 3072
#define MTOK (BATCH * SEQ)  // 8192

typedef __attribute__((ext_vector_type(8))) short short8;
typedef __attribute__((ext_vector_type(4))) short short4v;
typedef __attribute__((ext_vector_type(4))) float floatx4;

__device__ __forceinline__ short f2s(float x) {
  __hip_bfloat16 h = __float2bfloat16(x);
  return __builtin_bit_cast(short, h);
}
__device__ __forceinline__ float s2f(short s) {
  return __bfloat162float(__builtin_bit_cast(__hip_bfloat16, s));
}
__device__ __forceinline__ floatx4 zf4() {
  floatx4 v; v[0] = v[1] = v[2] = v[3] = 0.f; return v;
}
__device__ __forceinline__ float gelu_f(float x) {
  float z = 0.7978845608028654f * (x + 0.044715f * x * x * x);
  float u = __expf(2.f * z);
  return 0.5f * x * (2.f - 2.f / (u + 1.f));
}

// ---------- wave-per-row LayerNorm body (row fits one wave: 768 = 12x64) ----------
__device__ __forceinline__ void ln_row(const float* __restrict__ xr,
                                       const float* __restrict__ ls,
                                       const float* __restrict__ lb,
                                       short* __restrict__ yr, int lane) {
  float v[12];
  float s1 = 0.f, s2 = 0.f;
#pragma unroll
  for (int j = 0; j < 12; ++j) {
    v[j] = xr[lane + j * 64];
    s1 += v[j];
    s2 += v[j] * v[j];
  }
#pragma unroll
  for (int off = 32; off; off >>= 1) {
    s1 += __shfl_xor(s1, off, 64);
    s2 += __shfl_xor(s2, off, 64);
  }
  const float mu = s1 * (1.0f / DIM);
  const float var = s2 * (1.0f / DIM) - mu * mu;
  const float rstd = rsqrtf(fmaxf(var, 0.f) + 1e-6f);
#pragma unroll
  for (int j = 0; j < 12; ++j) {
    const int idx = lane + j * 64;
    yr[idx] = f2s((v[j] - mu) * rstd * ls[idx] + lb[idx]);
  }
}

// ---------- merged prologue: weight transposes (4 tiles/block) + LN1 (4 rows/block) ----------
__global__ __launch_bounds__(256) void pre_kernel(
    const float* __restrict__ w0, short* __restrict__ o0,
    const float* __restrict__ w1, short* __restrict__ o1,
    const float* __restrict__ w2, short* __restrict__ o2,
    const float* __restrict__ w3, short* __restrict__ o3,
    const float* __restrict__ x, const float* __restrict__ ls,
    const float* __restrict__ lb, short* __restrict__ y) {
  const int id = blockIdx.x;
  const int t = threadIdx.x;
  if (id < 1728) {
    __shared__ float tile[32][33];
    const int tx = t & 31, ty = t >> 5;
#pragma unroll
    for (int it = 0; it < 4; ++it) {
      const int gid = id * 4 + it;
      const float* in;
      short* out;
      int K, N, tid;
      if (gid < 1728)      { in = w0; out = o0; K = DIM; N = 3 * DIM; tid = gid; }
      else if (gid < 2304) { in = w1; out = o1; K = DIM; N = DIM;     tid = gid - 1728; }
      else if (gid < 4608) { in = w2; out = o2; K = DIM; N = HID;     tid = gid - 2304; }
      else                 { in = w3; out = o3; K = HID; N = DIM;     tid = gid - 4608; }
      const int ntx = N >> 5;
      const int n0 = (tid % ntx) * 32, k0 = (tid / ntx) * 32;
      if (it) __syncthreads();
#pragma unroll
      for (int i = 0; i < 4; ++i)
        tile[ty + i * 8][tx] = in[(size_t)(k0 + ty + i * 8) * N + n0 + tx];
      __syncthreads();
#pragma unroll
      for (int i = 0; i < 4; ++i)
        out[(size_t)(n0 + ty + i * 8) * K + k0 + tx] = f2s(tile[tx][ty + i * 8]);
    }
  } else {
    const int row = (id - 1728) * 4 + (t >> 6);
    const int lane = t & 63;
    ln_row(x + (size_t)row * DIM, ls, lb, y + (size_t)row * DIM, lane);
  }
}

// ---------- LayerNorm (standalone, for LN2): wave-per-row, 4 rows/block ----------
__global__ __launch_bounds__(256) void ln_kernel(const float* __restrict__ x,
                                                 const float* __restrict__ scale,
                                                 const float* __restrict__ bias,
                                                 short* __restrict__ y) {
  const int row = blockIdx.x * 4 + (threadIdx.x >> 6);
  const int lane = threadIdx.x & 63;
  ln_row(x + (size_t)row * DIM, scale, bias, y + (size_t)row * DIM, lane);
}

// ---------- async staging, 64-wide rows (8 chunks), xor-swizzled ----------
template <int ROWS, int THREADS>
__device__ __forceinline__ void stage8(const short* __restrict__ src, int ld,
                                       short* lds, int t) {
#pragma unroll
  for (int i = 0; i < (ROWS * 8) / THREADS; ++i) {
    const int S = i * THREADS + t;
    const int row = S >> 3;
    const int chunk = (S & 7) ^ (row & 7);
    const short* g = src + (size_t)row * ld + chunk * 8;
    const unsigned off = __builtin_amdgcn_readfirstlane((unsigned)((S & ~63) * 16));
    __builtin_amdgcn_global_load_lds(
        (const __attribute__((address_space(1))) void*)g,
        (__attribute__((address_space(3))) void*)((char*)lds + off), 16, 0, 0);
  }
}

// ---------- wide MFMA GEMM: 128x128 tile, 256 threads, BK=64; wave tile 64x64 ----------
// 12 K-steps at K=768; 32 MFMA/wave/step; 2-buffer double-buffering.
// MODE 0: qkv split -> Qb/Kb [bh][1024][64], Vtb [bh][64][1024]
// MODE 2: bf16 out + gelu
template <int MODE>
__global__ __launch_bounds__(256) void gemm_w128(
    const short* __restrict__ A, const short* __restrict__ Bt,
    const float* __restrict__ bias,
    short* __restrict__ outB,
    short* __restrict__ Qb, short* __restrict__ Kb, short* __restrict__ Vtb,
    int N, int K) {
  __shared__ __align__(16) short Asm[2][8192];   // 128 x 64 per buf
  __shared__ __align__(16) short Bsm[2][8192];   // 128 x 64 per buf
  const int t = threadIdx.x;
  const int lane = t & 63, w = t >> 6, quad = lane >> 4, l15 = lane & 15;

  const int nbx = gridDim.x;
  const int lid = blockIdx.y * nbx + blockIdx.x;
  const int xcd = lid & 7, local = lid >> 3;
  const int m0 = ((local / nbx) * 8 + xcd) * 128;
  const int n0 = (local % nbx) * 128;
  const int mb = (w & 1) * 64, nb = (w >> 1) * 64;

  floatx4 acc[4][4];
#pragma unroll
  for (int mi = 0; mi < 4; ++mi)
#pragma unroll
    for (int ni = 0; ni < 4; ++ni) acc[mi][ni] = zf4();

  stage8<128, 256>(A + (size_t)m0 * K, K, Asm[0], t);
  stage8<128, 256>(Bt + (size_t)n0 * K, K, Bsm[0], t);

  const int nk = K >> 6;  // 12
  for (int kt = 0; kt < nk; ++kt) {
    __syncthreads();
    const int cur = kt & 1;
    if (kt + 1 < nk) {
      stage8<128, 256>(A + (size_t)m0 * K + (kt + 1) * 64, K, Asm[cur ^ 1], t);
      stage8<128, 256>(Bt + (size_t)n0 * K + (kt + 1) * 64, K, Bsm[cur ^ 1], t);
    }
#pragma unroll
    for (int ks = 0; ks < 2; ++ks) {
      short8 a[4], b[4];
#pragma unroll
      for (int mi = 0; mi < 4; ++mi) {
        const int r = mb + mi * 16 + l15;
        a[mi] = *(const short8*)(Asm[cur] + r * 64 + (((ks * 4 + quad) ^ (r & 7)) * 8));
      }
#pragma unroll
      for (int ni = 0; ni < 4; ++ni) {
        const int r = nb + ni * 16 + l15;
        b[ni] = *(const short8*)(Bsm[cur] + r * 64 + (((ks * 4 + quad) ^ (r & 7)) * 8));
      }
#pragma unroll
      for (int mi = 0; mi < 4; ++mi)
#pragma unroll
        for (int ni = 0; ni < 4; ++ni)
          acc[mi][ni] = __builtin_amdgcn_mfma_f32_16x16x32_bf16(a[mi], b[ni], acc[mi][ni], 0, 0, 0);
    }
  }

#pragma unroll
  for (int mi = 0; mi < 4; ++mi) {
    const int row0 = m0 + mb + mi * 16 + quad * 4;
#pragma unroll
    for (int ni = 0; ni < 4; ++ni) {
      const int col = n0 + nb + ni * 16 + l15;
      const float bv = bias[col];
      float v[4];
#pragma unroll
      for (int r = 0; r < 4; ++r) v[r] = acc[mi][ni][r] + bv;
      if (MODE == 0) {
        const int bb = row0 >> 10;
        const int s0 = row0 & 1023;
        if (col < 1536) {
          const int cc = (col < 768) ? col : col - 768;
          const int h = cc >> 6, d = cc & 63;
          short* dst = (col < 768 ? Qb : Kb) + (size_t)(bb * NHEAD + h) * SEQ * HDIM;
#pragma unroll
          for (int r = 0; r < 4; ++r) dst[(size_t)(s0 + r) * HDIM + d] = f2s(v[r]);
        } else {
          const int cc = col - 1536;
          const int h = cc >> 6, d = cc & 63;
          short4v pv;
#pragma unroll
          for (int r = 0; r < 4; ++r) pv[r] = f2s(v[r]);
          *(short4v*)(Vtb + ((size_t)(bb * NHEAD + h) * HDIM + d) * SEQ + s0) = pv;
        }
      } else {
#pragma unroll
        for (int r = 0; r < 4; ++r)
          outB[(size_t)(row0 + r) * N + col] = f2s(gelu_f(v[r]));
      }
    }
  }
}

// ---------- MFMA GEMM (narrow N=64 tiles): 128x64 tile, 2 waves, BK=64 ----------
// (byte-identical to the R0 baseline)
__global__ __launch_bounds__(128) void gemm_n64(
    const short* __restrict__ A, const short* __restrict__ Bt,
    const float* __restrict__ bias, const float* __restrict__ res,
    float* __restrict__ outF, int N, int K) {
  __shared__ __align__(16) short Asm[2][8192];   // 128 x 64
  __shared__ __align__(16) short Bsm[2][4096];   // 64 x 64
  const int t = threadIdx.x;
  const int lane = t & 63, w = t >> 6, quad = lane >> 4, l15 = lane & 15;

  const int nbx = gridDim.x;   // 12
  const int lid = blockIdx.y * nbx + blockIdx.x;
  const int xcd = lid & 7, local = lid >> 3;
  const int m0 = ((local / nbx) * 8 + xcd) * 128;
  const int n0 = (local % nbx) * 64;
  const int mb = w * 64;

  floatx4 acc[4][4];
#pragma unroll
  for (int mi = 0; mi < 4; ++mi)
#pragma unroll
    for (int ni = 0; ni < 4; ++ni) acc[mi][ni] = zf4();

  stage8<128, 128>(A + (size_t)m0 * K, K, Asm[0], t);
  stage8<64, 128>(Bt + (size_t)n0 * K, K, Bsm[0], t);

  const int nk = K >> 6;
  for (int kt = 0; kt < nk; ++kt) {
    __syncthreads();
    const int cur = kt & 1;
    if (kt + 1 < nk) {
      stage8<128, 128>(A + (size_t)m0 * K + (kt + 1) * 64, K, Asm[cur ^ 1], t);
      stage8<64, 128>(Bt + (size_t)n0 * K + (kt + 1) * 64, K, Bsm[cur ^ 1], t);
    }
#pragma unroll
    for (int ks = 0; ks < 2; ++ks) {
      short8 a[4], b[4];
#pragma unroll
      for (int mi = 0; mi < 4; ++mi) {
        const int r = mb + mi * 16 + l15;
        a[mi] = *(const short8*)(Asm[cur] + r * 64 + (((ks * 4 + quad) ^ (r & 7)) * 8));
      }
#pragma unroll
      for (int ni = 0; ni < 4; ++ni) {
        const int r = ni * 16 + l15;
        b[ni] = *(const short8*)(Bsm[cur] + r * 64 + (((ks * 4 + quad) ^ (r & 7)) * 8));
      }
#pragma unroll
      for (int mi = 0; mi < 4; ++mi)
#pragma unroll
        for (int ni = 0; ni < 4; ++ni)
          acc[mi][ni] = __builtin_amdgcn_mfma_f32_16x16x32_bf16(a[mi], b[ni], acc[mi][ni], 0, 0, 0);
    }
  }

#pragma unroll
  for (int mi = 0; mi < 4; ++mi) {
    const int row0 = m0 + mb + mi * 16 + quad * 4;
#pragma unroll
    for (int ni = 0; ni < 4; ++ni) {
      const int col = n0 + ni * 16 + l15;
      const float bv = bias[col];
#pragma unroll
      for (int r = 0; r < 4; ++r) {
        const size_t idx = (size_t)(row0 + r) * N + col;
        outF[idx] = acc[mi][ni][r] + bv + res[idx];
      }
    }
  }
}

// ---------- attention: S^T = K Q^T, O^T = V^T P^T; KT=64, double-buffered ----------
// (byte-identical to the R0 baseline)
__device__ __forceinline__ void stage64(const short* __restrict__ src, int ld,
                                        short* lds, int t) {
  const int lane = t & 63, w = t >> 6;
#pragma unroll
  for (int i = 0; i < 2; ++i) {
    const int S = w * 128 + i * 64 + lane;
    const int r = S >> 3, c0 = S & 7;
    const int c = c0 ^ (r & 7);
    const short* g = src + (size_t)r * ld + c * 8;
    const unsigned off = __builtin_amdgcn_readfirstlane((unsigned)((w * 128 + i * 64) * 16));
    __builtin_amdgcn_global_load_lds(
        (const __attribute__((address_space(1))) void*)g,
        (__attribute__((address_space(3))) void*)((char*)lds + off), 16, 0, 0);
  }
}

__global__ __launch_bounds__(256) void attn_kernel(
    const short* __restrict__ Qb, const short* __restrict__ Kb,
    const short* __restrict__ Vtb, short* __restrict__ o) {
  __shared__ __align__(16) short Ks[2][4096];
  __shared__ __align__(16) short Vts[2][4096];
  __shared__ __align__(16) short Pt[8192];
  const int t = threadIdx.x;
  const int lane = t & 63, w = t >> 6, quad = lane >> 4, l15 = lane & 15;
  const int bh = blockIdx.x;           // 0..95
  const int q0 = blockIdx.y * 128;     // 0..7 tiles
  const size_t qkbase = (size_t)bh * SEQ * HDIM;
  const size_t vbase = (size_t)bh * HDIM * SEQ;
  short* ptw = Pt + w * 2048;
  const float cexp = 0.18033688011f;  // 0.125 * log2(e)

  short8 bq[2][2];
#pragma unroll
  for (int mi = 0; mi < 2; ++mi)
#pragma unroll
    for (int ks = 0; ks < 2; ++ks)
      bq[mi][ks] = *(const short8*)(Qb + qkbase +
                                    (size_t)(q0 + w * 32 + mi * 16 + l15) * HDIM +
                                    ks * 32 + quad * 8);

  floatx4 oacc[4][2];
  float l_acc[2] = {0.f, 0.f};
#pragma unroll
  for (int di = 0; di < 4; ++di)
#pragma unroll
    for (int mi = 0; mi < 2; ++mi) oacc[di][mi] = zf4();

  stage64(Kb + qkbase, HDIM, Ks[0], t);
  stage64(Vtb + vbase, SEQ, Vts[0], t);

  for (int kt = 0; kt < 16; ++kt) {
    __syncthreads();
    const int cur = kt & 1;
    if (kt < 15) {
      stage64(Kb + qkbase + (size_t)(kt + 1) * 64 * HDIM, HDIM, Ks[cur ^ 1], t);
      stage64(Vtb + vbase + (kt + 1) * 64, SEQ, Vts[cur ^ 1], t);
    }

    floatx4 sacc[4][2];
#pragma unroll
    for (int ni = 0; ni < 4; ++ni)
#pragma unroll
      for (int mi = 0; mi < 2; ++mi) sacc[ni][mi] = zf4();
#pragma unroll
    for (int ks = 0; ks < 2; ++ks) {
      short8 ak[4];
#pragma unroll
      for (int ni = 0; ni < 4; ++ni) {
        const int r = ni * 16 + l15;
        ak[ni] = *(const short8*)(Ks[cur] + r * 64 + (((ks * 4 + quad) ^ (r & 7)) * 8));
      }
#pragma unroll
      for (int ni = 0; ni < 4; ++ni)
#pragma unroll
        for (int mi = 0; mi < 2; ++mi)
          sacc[ni][mi] = __builtin_amdgcn_mfma_f32_16x16x32_bf16(ak[ni], bq[mi][ks], sacc[ni][mi], 0, 0, 0);
    }

#pragma unroll
    for (int mi = 0; mi < 2; ++mi) {
      const int row = mi * 16 + l15;
      const int swz = (row & 7) ^ ((row & 8) >> 1);
#pragma unroll
      for (int ni = 0; ni < 4; ++ni) {
        short4v pk;
#pragma unroll
        for (int r = 0; r < 4; ++r) {
          const float p = exp2f(sacc[ni][mi][r] * cexp);
          l_acc[mi] += p;
          pk[r] = f2s(p);
        }
        const int c = ni * 2 + (quad >> 1);
        *(short4v*)(ptw + row * 64 + ((c ^ swz) * 8 + (quad & 1) * 4)) = pk;
      }
    }

#pragma unroll
    for (int ks = 0; ks < 2; ++ks) {
      short8 bp[2];
#pragma unroll
      for (int mi = 0; mi < 2; ++mi) {
        const int row = mi * 16 + l15;
        const int swz = (row & 7) ^ ((row & 8) >> 1);
        bp[mi] = *(const short8*)(ptw + row * 64 + (((ks * 4 + quad) ^ swz) * 8));
      }
      short8 av[4];
#pragma unroll
      for (int di = 0; di < 4; ++di) {
        const int r = di * 16 + l15;
        av[di] = *(const short8*)(Vts[cur] + r * 64 + (((ks * 4 + quad) ^ (r & 7)) * 8));
      }
#pragma unroll
      for (int di = 0; di < 4; ++di)
#pragma unroll
        for (int mi = 0; mi < 2; ++mi)
          oacc[di][mi] = __builtin_amdgcn_mfma_f32_16x16x32_bf16(av[di], bp[mi], oacc[di][mi], 0, 0, 0);
    }
  }

  const int bb = bh / NHEAD, hh = bh % NHEAD;
  float inv[2];
#pragma unroll
  for (int mi = 0; mi < 2; ++mi) {
    float l = l_acc[mi];
    l += __shfl_xor(l, 16, 64);
    l += __shfl_xor(l, 32, 64);
    inv[mi] = 1.0f / l;
  }
#pragma unroll
  for (int di = 0; di < 4; ++di)
#pragma unroll
    for (int mi = 0; mi < 2; ++mi) {
      const int tok = bb * SEQ + q0 + w * 32 + mi * 16 + l15;
      const int d = hh * HDIM + di * 16 + quad * 4;
      short4v ov;
#pragma unroll
      for (int r = 0; r < 4; ++r) ov[r] = f2s(oacc[di][mi][r] * inv[mi]);
      *(short4v*)(o + (size_t)tok * DIM + d) = ov;
    }
}

extern "C" void kernel_launch(void* const* d_in, const int* in_sizes, int n_in,
                              void* d_out, int out_size, void* d_ws, size_t ws_size,
                              hipStream_t stream) {
  const float* x      = (const float*)d_in[0];
  const float* ln1_s  = (const float*)d_in[1];
  const float* ln1_b  = (const float*)d_in[2];
  const float* qkv_w  = (const float*)d_in[3];
  const float* qkv_b  = (const float*)d_in[4];
  const float* proj_w = (const float*)d_in[5];
  const float* proj_b = (const float*)d_in[6];
  const float* ln2_s  = (const float*)d_in[7];
  const float* ln2_b  = (const float*)d_in[8];
  const float* fc1_w  = (const float*)d_in[9];
  const float* fc1_b  = (const float*)d_in[10];
  const float* fc2_w  = (const float*)d_in[11];
  const float* fc2_b  = (const float*)d_in[12];
  float* out = (float*)d_out;

  char* p = (char*)d_ws;
  short* wqt = (short*)p; p += (size_t)(3 * DIM) * DIM * 2;
  short* wpt = (short*)p; p += (size_t)DIM * DIM * 2;
  short* w1t = (short*)p; p += (size_t)HID * DIM * 2;
  short* w2t = (short*)p; p += (size_t)DIM * HID * 2;
  short* y   = (short*)p; p += (size_t)MTOK * DIM * 2;
  short* Qb  = (short*)p; p += (size_t)MTOK * DIM * 2;
  short* Kb  = (short*)p; p += (size_t)MTOK * DIM * 2;
  short* Vtb = (short*)p; p += (size_t)MTOK * DIM * 2;
  float* x1  = (float*)p; p += (size_t)MTOK * DIM * 4;
  short* h   = (short*)p; p += (size_t)MTOK * HID * 2;
  short* obuf = y;
  short* y2   = Qb;

  // prologue: weight transposes (4 tiles/block) + LN1 (wave-per-row) merged
  pre_kernel<<<1728 + MTOK / 4, 256, 0, stream>>>(qkv_w, wqt, proj_w, wpt, fc1_w, w1t,
                                                  fc2_w, w2t, x, ln1_s, ln1_b, y);
  // qkv: 128x128 tiles (2304 = 18 x 128)
  gemm_w128<0><<<dim3(18, 64), 256, 0, stream>>>(
      y, wqt, qkv_b, nullptr, Qb, Kb, Vtb, 3 * DIM, DIM);
  // attention: grid (bh, qt) for XCD L2 reuse of K/V
  attn_kernel<<<dim3(BATCH * NHEAD, SEQ / 128), 256, 0, stream>>>(Qb, Kb, Vtb, obuf);
  gemm_n64<<<dim3(12, 64), 128, 0, stream>>>(
      obuf, wpt, proj_b, x, x1, DIM, DIM);
  ln_kernel<<<MTOK / 4, 256, 0, stream>>>(x1, ln2_s, ln2_b, y2);
  // fc1: 128x128 tiles (3072 = 24 x 128)
  gemm_w128<2><<<dim3(24, 64), 256, 0, stream>>>(
      y2, w1t, fc1_b, h, nullptr, nullptr, nullptr, HID, DIM);
  gemm_n64<<<dim3(12, 64), 128, 0, stream>>>(
      h, w2t, fc2_b, x1, out, DIM, HID);
}